// Round 3
// baseline (152.935 us; speedup 1.0000x reference)
//
#include <hip/hip_runtime.h>
#include <hip/hip_bf16.h>

typedef float f32x4 __attribute__((ext_vector_type(4)));
typedef short s16x8 __attribute__((ext_vector_type(8)));

#define D_DIM 4096
#define NT 24            // 16-wide col tiles
#define DSTRIDE 388      // Dmat padded stride

__device__ __forceinline__ unsigned short f2bf(float f) {
    unsigned u = __float_as_uint(f);
    u += 0x7fffu + ((u >> 16) & 1u);   // RNE
    return (unsigned short)(u >> 16);
}

__device__ __forceinline__ s16x8 cvt8(f32x4 a, f32x4 b) {
    s16x8 r;
    r[0] = (short)f2bf(a.x); r[1] = (short)f2bf(a.y);
    r[2] = (short)f2bf(a.z); r[3] = (short)f2bf(a.w);
    r[4] = (short)f2bf(b.x); r[5] = (short)f2bf(b.y);
    r[6] = (short)f2bf(b.z); r[7] = (short)f2bf(b.w);
    return r;
}

__device__ __forceinline__ float sin8(f32x4 a, f32x4 b) {
    return __sinf(a.x) + __sinf(a.y) + __sinf(a.z) + __sinf(a.w)
         + __sinf(b.x) + __sinf(b.y) + __sinf(b.z) + __sinf(b.w);
}

__global__ __launch_bounds__(64) void reg_init_kernel(const float* __restrict__ C,
                                                      const float* __restrict__ Csin,
                                                      float* __restrict__ reg_out) {
    if (threadIdx.x == 0)
        reg_out[0] = 0.05f * (fabsf(C[0]) + fabsf(C[1]) + fabsf(C[2]) + fabsf(Csin[0]));
}

// Build W [4096 x 384] bf16 in MFMA B-fragment-packed layout:
// element (k, n): chunk = (k>>5)*NT + (n>>4); lane = ((k&31)>>3)*16 | (n&15); j = k&7
__global__ __launch_bounds__(64) void build_w_kernel(const float* __restrict__ U1,
                                                     const float* __restrict__ U2,
                                                     const float* __restrict__ U3,
                                                     unsigned short* __restrict__ W,
                                                     float* __restrict__ reg_out) {
    const int ks = blockIdx.x / NT;
    const int ct = blockIdx.x % NT;
    const int l  = threadIdx.x;
    const int n  = ct * 16 + (l & 15);
    const int kb = ks * 32 + ((l >> 4) << 3);

    const float* src;
    float scale;
    if (n < 64)       { src = U1 + n;                  scale = 0.01f / 262144.f; }
    else if (n < 128) { src = U2 + (n - 64);           scale = 0.01f / 524288.f; }
    else if (n < 192) { src = U2 + 262144 + (n - 128); scale = 0.01f / 524288.f; }
    else if (n < 256) { src = U3 + (n - 192);          scale = 0.01f / 786432.f; }
    else if (n < 320) { src = U3 + 262144 + (n - 256); scale = 0.01f / 786432.f; }
    else              { src = U3 + 524288 + (n - 320); scale = 0.01f / 786432.f; }

    unsigned short h[8];
    float sabs = 0.f;
#pragma unroll
    for (int j = 0; j < 8; ++j) {
        float u = src[(size_t)(kb + j) * 64];
        sabs += fabsf(u);
        h[j] = f2bf(u);
    }
    uint4 pk;
    pk.x = (unsigned)h[0] | ((unsigned)h[1] << 16);
    pk.y = (unsigned)h[2] | ((unsigned)h[3] << 16);
    pk.z = (unsigned)h[4] | ((unsigned)h[5] << 16);
    pk.w = (unsigned)h[6] | ((unsigned)h[7] << 16);
    *(uint4*)(W + ((size_t)blockIdx.x * 64 + l) * 8) = pk;

    sabs *= scale;
#pragma unroll
    for (int off = 32; off >= 1; off >>= 1)
        sabs += __shfl_xor(sabs, off, 64);
    if (l == 0) atomicAdd(reg_out, sabs);
}

// Barrier-free fused kernel. Block = 512 thr = 8 waves = 2 row-sets x 4 col-groups.
// Wave owns 16 rows x 6 col-tiles; A fragments loaded directly from global X
// (lane l: row l&15, k-chunk (l>>4)*8), B from L2-resident frag-packed W.
// Single __syncthreads before the in-LDS nonlinear combine.
__global__ __launch_bounds__(512) void poly_main_kernel(const float* __restrict__ X,
                                                        const unsigned short* __restrict__ W,
                                                        const float* __restrict__ C,
                                                        const float* __restrict__ beta,
                                                        const float* __restrict__ Csin,
                                                        float* __restrict__ out) {
    __shared__ float Dmat[32][DSTRIDE];   // 49.7 KB
    __shared__ float sinrow[32];

    const int t    = threadIdx.x;
    const int lane = t & 63;
    const int wv   = t >> 6;
    const int rs   = wv >> 2;             // row-set 0/1
    const int cg   = wv & 3;              // col-group 0..3
    const int ct0  = cg * 6;              // first col-tile
    const int row0 = blockIdx.x * 32;
    const int arow = row0 + rs * 16 + (lane & 15);

    const float* xp = X + (size_t)arow * D_DIM + ((lane >> 4) << 3);
    const s16x8* __restrict__ Wf = (const s16x8*)W;
    const size_t wl = (size_t)ct0 * 64 + lane;

    f32x4 acc[6];
#pragma unroll
    for (int c = 0; c < 6; ++c) acc[c] = (f32x4){0.f, 0.f, 0.f, 0.f};
    float sinacc = 0.f;

    f32x4 xa0, xb0, xa1, xb1;
    s16x8 b0[6], b1[6];

#define LOADK(s, XA, XB, BB)                                            \
    {                                                                   \
        XA = *(const f32x4*)(xp + (size_t)(s) * 32);                    \
        XB = *(const f32x4*)(xp + (size_t)(s) * 32 + 4);                \
        _Pragma("unroll")                                               \
        for (int c = 0; c < 6; ++c)                                     \
            BB[c] = Wf[wl + ((size_t)(s) * NT + c) * 64];               \
    }

#define COMPUTE(XA, XB, BB)                                             \
    {                                                                   \
        if (cg == 0) sinacc += sin8(XA, XB);                            \
        s16x8 af = cvt8(XA, XB);                                        \
        _Pragma("unroll")                                               \
        for (int c = 0; c < 6; ++c)                                     \
            acc[c] = __builtin_amdgcn_mfma_f32_16x16x32_bf16(af, BB[c], acc[c], 0, 0, 0); \
    }

    LOADK(0, xa0, xb0, b0);
    LOADK(1, xa1, xb1, b1);
    for (int s = 0; s < 126; s += 2) {
        COMPUTE(xa0, xb0, b0);
        LOADK(s + 2, xa0, xb0, b0);
        COMPUTE(xa1, xb1, b1);
        LOADK(s + 3, xa1, xb1, b1);
    }
    COMPUTE(xa0, xb0, b0);
    COMPUTE(xa1, xb1, b1);
#undef LOADK
#undef COMPUTE

    // ---- epilogue ----
    const int lr4 = (lane >> 4) << 2;
    const int lc  = lane & 15;
#pragma unroll
    for (int c = 0; c < 6; ++c) {
        const int col = (ct0 + c) * 16 + lc;
#pragma unroll
        for (int i = 0; i < 4; ++i)
            Dmat[rs * 16 + lr4 + i][col] = acc[c][i];
    }

    if (cg == 0) {
        sinacc += __shfl_xor(sinacc, 16, 64);
        sinacc += __shfl_xor(sinacc, 32, 64);
        if (lane < 16) sinrow[rs * 16 + lane] = sinacc;
    }
    __syncthreads();

    const int crow = t >> 4;   // 0..31
    const int cc   = t & 15;
    float t1 = 0.f, t2 = 0.f, t3 = 0.f;
#pragma unroll
    for (int rr = 0; rr < 64; rr += 16) {
        const int r = rr + cc;
        t1 += Dmat[crow][r];
        t2 += Dmat[crow][64 + r]  * Dmat[crow][128 + r];
        t3 += Dmat[crow][192 + r] * Dmat[crow][256 + r] * Dmat[crow][320 + r];
    }
#pragma unroll
    for (int off = 1; off < 16; off <<= 1) {
        t1 += __shfl_xor(t1, off, 16);
        t2 += __shfl_xor(t2, off, 16);
        t3 += __shfl_xor(t3, off, 16);
    }
    if (cc == 0)
        out[row0 + crow] = beta[0] + C[0] * t1 + C[1] * t2 + C[2] * t3
                         + Csin[0] * sinrow[crow];
}

extern "C" void kernel_launch(void* const* d_in, const int* in_sizes, int n_in,
                              void* d_out, int out_size, void* d_ws, size_t ws_size,
                              hipStream_t stream) {
    const float* X   = (const float*)d_in[0];
    const float* U1  = (const float*)d_in[1];
    const float* U2  = (const float*)d_in[2];
    const float* U3  = (const float*)d_in[3];
    const float* Cc  = (const float*)d_in[4];
    const float* bet = (const float*)d_in[5];
    const float* Cs  = (const float*)d_in[6];
    float* out = (float*)d_out;
    unsigned short* W = (unsigned short*)d_ws;   // 3 MiB bf16, frag-packed

    reg_init_kernel<<<1, 64, 0, stream>>>(Cc, Cs, out + 8192);
    build_w_kernel<<<128 * NT, 64, 0, stream>>>(U1, U2, U3, W, out + 8192);
    poly_main_kernel<<<256, 512, 0, stream>>>(X, W, Cc, bet, Cs, out);
}

// Round 4
// 128.828 us; speedup vs baseline: 1.1871x; 1.1871x over previous
//
#include <hip/hip_runtime.h>
#include <hip/hip_bf16.h>

typedef float f32x4 __attribute__((ext_vector_type(4)));
typedef short s16x8 __attribute__((ext_vector_type(8)));

#define D_DIM 4096
#define NT 24            // 16-wide col tiles
#define NSLAB 128        // K slabs of 32
#define BM 32
#define DSTRIDE 388
// LDS pool byte offsets
#define B_OFF 0          // Bbuf[2][24576]
#define A_OFF 49152      // Abuf[2][2048]
#define SIN_OFF 53248    // sinrow[32]
#define POOL_BYTES 53376

__device__ __forceinline__ unsigned short f2bf(float f) {
    unsigned u = __float_as_uint(f);
    u += 0x7fffu + ((u >> 16) & 1u);   // RNE
    return (unsigned short)(u >> 16);
}

__device__ __forceinline__ void gload16(const void* g, void* l) {
    __builtin_amdgcn_global_load_lds(
        (const __attribute__((address_space(1))) unsigned int*)g,
        (__attribute__((address_space(3))) unsigned int*)l, 16, 0, 0);
}

__global__ __launch_bounds__(64) void reg_init_kernel(const float* __restrict__ C,
                                                      const float* __restrict__ Csin,
                                                      float* __restrict__ reg_out) {
    if (threadIdx.x == 0)
        reg_out[0] = 0.05f * (fabsf(C[0]) + fabsf(C[1]) + fabsf(C[2]) + fabsf(Csin[0]));
}

// Build W [4096 x 384] bf16, MFMA B-fragment-packed, slab-contiguous:
// chunk = (k>>5)*NT + (n>>4); lane = ((k&31)>>3)*16 | (n&15); j = k&7.
// Slab s (32 k's) occupies bytes [s*24576, (s+1)*24576) — contiguous.
__global__ __launch_bounds__(64) void build_w_kernel(const float* __restrict__ U1,
                                                     const float* __restrict__ U2,
                                                     const float* __restrict__ U3,
                                                     unsigned short* __restrict__ W,
                                                     float* __restrict__ reg_out) {
    const int ks = blockIdx.x / NT;
    const int ct = blockIdx.x % NT;
    const int l  = threadIdx.x;
    const int n  = ct * 16 + (l & 15);
    const int kb = ks * 32 + ((l >> 4) << 3);

    const float* src;
    float scale;
    if (n < 64)       { src = U1 + n;                  scale = 0.01f / 262144.f; }
    else if (n < 128) { src = U2 + (n - 64);           scale = 0.01f / 524288.f; }
    else if (n < 192) { src = U2 + 262144 + (n - 128); scale = 0.01f / 524288.f; }
    else if (n < 256) { src = U3 + (n - 192);          scale = 0.01f / 786432.f; }
    else if (n < 320) { src = U3 + 262144 + (n - 256); scale = 0.01f / 786432.f; }
    else              { src = U3 + 524288 + (n - 320); scale = 0.01f / 786432.f; }

    unsigned short h[8];
    float sabs = 0.f;
#pragma unroll
    for (int j = 0; j < 8; ++j) {
        float u = src[(size_t)(kb + j) * 64];
        sabs += fabsf(u);
        h[j] = f2bf(u);
    }
    uint4 pk;
    pk.x = (unsigned)h[0] | ((unsigned)h[1] << 16);
    pk.y = (unsigned)h[2] | ((unsigned)h[3] << 16);
    pk.z = (unsigned)h[4] | ((unsigned)h[5] << 16);
    pk.w = (unsigned)h[6] | ((unsigned)h[7] << 16);
    *(uint4*)(W + ((size_t)blockIdx.x * 64 + l) * 8) = pk;

    sabs *= scale;
#pragma unroll
    for (int off = 32; off >= 1; off >>= 1)
        sabs += __shfl_xor(sabs, off, 64);
    if (l == 0) atomicAdd(reg_out, sabs);
}

// 1024 thr = 16 waves; block owns 32 rows x 384 cols x K=4096.
// Per kstep (BK=32): B slab (24KB) global_load_lds by waves 4..15;
// A slab (32x32) staged f32->bf16 by threads 0..255 (+ sin); double-buffered,
// one __syncthreads per kstep (2-phase schedule). Wave (rs,cg): 1 A-frag x 3 B-frags.
__global__ __launch_bounds__(1024) void poly_main_kernel(const float* __restrict__ X,
                                                         const unsigned short* __restrict__ W,
                                                         const float* __restrict__ C,
                                                         const float* __restrict__ beta,
                                                         const float* __restrict__ Csin,
                                                         float* __restrict__ out) {
    __shared__ __align__(16) char pool[POOL_BYTES];
    float (*Dmat)[DSTRIDE] = (float(*)[DSTRIDE])pool;      // epilogue alias
    float* sinrow = (float*)(pool + SIN_OFF);

    const int t    = threadIdx.x;
    const int lane = t & 63;
    const int wv   = t >> 6;          // 0..15
    const int rs   = wv >> 3;         // row-set 0/1
    const int cg   = wv & 7;          // col-group 0..7 (3 tiles each)
    const int row0 = blockIdx.x * BM;

    // compute-side LDS byte offsets (+buf stride)
    const int a_rd = A_OFF + rs * 1024 + lane * 16;
    const int b_rd = B_OFF + cg * 3072 + lane * 16;

    // A staging: threads 0..255 -> row sr, k4..k4+3 of each slab
    const bool isA = (t < 256);
    const int sr = (t >> 3) & 31;
    const int k4 = (t & 7) << 2;
    const float* xp = X + (size_t)(row0 + sr) * D_DIM + k4;
    const int aw = A_OFF + (sr >> 4) * 1024
                 + (((((k4 >> 3) & 3) << 4) | (sr & 15)) * 16) + ((k4 & 7) << 1);

    // B staging: waves 4..15, two 1KB issues each
    const bool isB = (wv >= 4);
    const int bi = isB ? (wv - 4) * 2 : 0;
    const unsigned short* wp = W + bi * 512 + lane * 8;    // +s*12288 shorts
    const int bw = B_OFF + bi * 1024;                       // +buf*24576

    f32x4 acc[3];
#pragma unroll
    for (int c = 0; c < 3; ++c) acc[c] = (f32x4){0.f, 0.f, 0.f, 0.f};
    float sinacc = 0.f;
    f32x4 xcur = (f32x4){0.f, 0.f, 0.f, 0.f};

    // ---- prologue: stage slab 0 into buf0, prefetch x slab1 ----
    if (isA) {
        f32x4 x0 = *(const f32x4*)xp;
        sinacc += __sinf(x0.x) + __sinf(x0.y) + __sinf(x0.z) + __sinf(x0.w);
        short4 h;
        h.x = (short)f2bf(x0.x); h.y = (short)f2bf(x0.y);
        h.z = (short)f2bf(x0.z); h.w = (short)f2bf(x0.w);
        *(short4*)(pool + aw) = h;
        xcur = *(const f32x4*)(xp + 32);
    }
    if (isB) {
        gload16(wp, pool + bw);
        gload16(wp + 512, pool + bw + 1024);
    }
    __syncthreads();

    // ---- main loop: one barrier per kstep ----
    for (int s = 0; s < NSLAB; ++s) {
        const int buf = s & 1;
        const int nb  = buf ^ 1;

        if (isB && s < NSLAB - 1) {                 // issue next B slab (async)
            const unsigned short* w2 = wp + (size_t)(s + 1) * 12288;
            gload16(w2, pool + bw + nb * 24576);
            gload16(w2 + 512, pool + bw + nb * 24576 + 1024);
        }
        f32x4 xnxt = xcur;
        if (isA && s < NSLAB - 2)                    // prefetch x slab s+2
            xnxt = *(const f32x4*)(xp + (size_t)(s + 2) * 32);

        // current frags
        s16x8 af  = *(const s16x8*)(pool + a_rd + buf * 2048);
        s16x8 bf0 = *(const s16x8*)(pool + b_rd + buf * 24576);
        s16x8 bf1 = *(const s16x8*)(pool + b_rd + buf * 24576 + 1024);
        s16x8 bf2 = *(const s16x8*)(pool + b_rd + buf * 24576 + 2048);
        acc[0] = __builtin_amdgcn_mfma_f32_16x16x32_bf16(af, bf0, acc[0], 0, 0, 0);
        acc[1] = __builtin_amdgcn_mfma_f32_16x16x32_bf16(af, bf1, acc[1], 0, 0, 0);
        acc[2] = __builtin_amdgcn_mfma_f32_16x16x32_bf16(af, bf2, acc[2], 0, 0, 0);

        if (isA && s < NSLAB - 1) {                  // write next A slab
            sinacc += __sinf(xcur.x) + __sinf(xcur.y) + __sinf(xcur.z) + __sinf(xcur.w);
            short4 h;
            h.x = (short)f2bf(xcur.x); h.y = (short)f2bf(xcur.y);
            h.z = (short)f2bf(xcur.z); h.w = (short)f2bf(xcur.w);
            *(short4*)(pool + aw + nb * 2048) = h;
            xcur = xnxt;
        }
        __syncthreads();
    }

    // ---- epilogue (Dmat aliases B buffers; all LDS reads drained) ----
    const int lr4 = (lane >> 4) << 2;
    const int lc  = lane & 15;
#pragma unroll
    for (int c = 0; c < 3; ++c) {
        const int col = (cg * 3 + c) * 16 + lc;
#pragma unroll
        for (int i = 0; i < 4; ++i)
            Dmat[rs * 16 + lr4 + i][col] = acc[c][i];
    }
    if (isA) {
        sinacc += __shfl_xor(sinacc, 1);
        sinacc += __shfl_xor(sinacc, 2);
        sinacc += __shfl_xor(sinacc, 4);
        if ((t & 7) == 0) sinrow[sr] = sinacc;
    }
    __syncthreads();

    if (t < 512) {
        const int crow = t >> 4;   // 0..31
        const int cc   = t & 15;
        float t1 = 0.f, t2 = 0.f, t3 = 0.f;
#pragma unroll
        for (int rr = 0; rr < 64; rr += 16) {
            const int r = rr + cc;
            t1 += Dmat[crow][r];
            t2 += Dmat[crow][64 + r]  * Dmat[crow][128 + r];
            t3 += Dmat[crow][192 + r] * Dmat[crow][256 + r] * Dmat[crow][320 + r];
        }
#pragma unroll
        for (int off = 1; off < 16; off <<= 1) {
            t1 += __shfl_xor(t1, off, 16);
            t2 += __shfl_xor(t2, off, 16);
            t3 += __shfl_xor(t3, off, 16);
        }
        if (cc == 0)
            out[row0 + crow] = beta[0] + C[0] * t1 + C[1] * t2 + C[2] * t3
                             + Csin[0] * sinrow[crow];
    }
}

extern "C" void kernel_launch(void* const* d_in, const int* in_sizes, int n_in,
                              void* d_out, int out_size, void* d_ws, size_t ws_size,
                              hipStream_t stream) {
    const float* X   = (const float*)d_in[0];
    const float* U1  = (const float*)d_in[1];
    const float* U2  = (const float*)d_in[2];
    const float* U3  = (const float*)d_in[3];
    const float* Cc  = (const float*)d_in[4];
    const float* bet = (const float*)d_in[5];
    const float* Cs  = (const float*)d_in[6];
    float* out = (float*)d_out;
    unsigned short* W = (unsigned short*)d_ws;   // 3 MiB bf16, frag-packed

    reg_init_kernel<<<1, 64, 0, stream>>>(Cc, Cs, out + 8192);
    build_w_kernel<<<128 * NT, 64, 0, stream>>>(U1, U2, U3, W, out + 8192);
    poly_main_kernel<<<256, 1024, 0, stream>>>(X, W, Cc, bet, Cs, out);
}

// Round 5
// 94.635 us; speedup vs baseline: 1.6160x; 1.3613x over previous
//
#include <hip/hip_runtime.h>
#include <hip/hip_bf16.h>

typedef float f32x4 __attribute__((ext_vector_type(4)));
typedef short s16x8 __attribute__((ext_vector_type(8)));

#define D_DIM 4096
#define NT 24            // 16-wide col tiles
#define NSLAB 128        // K slabs of 32
#define BM 32
#define DSTRIDE 388      // Dmat row stride (floats)
#define SIN_OFF 49664    // sinpart[2][32] after Dmat 32*388*4
#define POOL_BYTES 49920

__device__ __forceinline__ unsigned short f2bf(float f) {
    unsigned u = __float_as_uint(f);
    u += 0x7fffu + ((u >> 16) & 1u);   // RNE
    return (unsigned short)(u >> 16);
}

__global__ __launch_bounds__(64) void reg_init_kernel(const float* __restrict__ C,
                                                      const float* __restrict__ Csin,
                                                      float* __restrict__ reg_out) {
    if (threadIdx.x == 0)
        reg_out[0] = 0.05f * (fabsf(C[0]) + fabsf(C[1]) + fabsf(C[2]) + fabsf(Csin[0]));
}

// Build W [4096 x 384] bf16, MFMA B-fragment-packed, slab-contiguous:
// chunk = (k>>5)*NT + (n>>4); lane = ((k&31)>>3)*16 | (n&15); j = k&7.
__global__ __launch_bounds__(64) void build_w_kernel(const float* __restrict__ U1,
                                                     const float* __restrict__ U2,
                                                     const float* __restrict__ U3,
                                                     unsigned short* __restrict__ W,
                                                     float* __restrict__ reg_out) {
    const int ks = blockIdx.x / NT;
    const int ct = blockIdx.x % NT;
    const int l  = threadIdx.x;
    const int n  = ct * 16 + (l & 15);
    const int kb = ks * 32 + ((l >> 4) << 3);

    const float* src;
    float scale;
    if (n < 64)       { src = U1 + n;                  scale = 0.01f / 262144.f; }
    else if (n < 128) { src = U2 + (n - 64);           scale = 0.01f / 524288.f; }
    else if (n < 192) { src = U2 + 262144 + (n - 128); scale = 0.01f / 524288.f; }
    else if (n < 256) { src = U3 + (n - 192);          scale = 0.01f / 786432.f; }
    else if (n < 320) { src = U3 + 262144 + (n - 256); scale = 0.01f / 786432.f; }
    else              { src = U3 + 524288 + (n - 320); scale = 0.01f / 786432.f; }

    unsigned short h[8];
    float sabs = 0.f;
#pragma unroll
    for (int j = 0; j < 8; ++j) {
        float u = src[(size_t)(kb + j) * 64];
        sabs += fabsf(u);
        h[j] = f2bf(u);
    }
    uint4 pk;
    pk.x = (unsigned)h[0] | ((unsigned)h[1] << 16);
    pk.y = (unsigned)h[2] | ((unsigned)h[3] << 16);
    pk.z = (unsigned)h[4] | ((unsigned)h[5] << 16);
    pk.w = (unsigned)h[6] | ((unsigned)h[7] << 16);
    *(uint4*)(W + ((size_t)blockIdx.x * 64 + l) * 8) = pk;

    sabs *= scale;
#pragma unroll
    for (int off = 32; off >= 1; off >>= 1)
        sabs += __shfl_xor(sabs, off, 64);
    if (l == 0) atomicAdd(reg_out, sabs);
}

// 1024 thr = 16 waves = 2 K-parity groups (kg) x 8 col-groups (cg, 3 tiles each).
// Wave (kg,cg): ksteps s==kg (mod 2), 32 rows x 48 cols; B frags read straight
// from L2-resident frag-packed W into regs (2 ksteps ahead); A slab (32x32 bf16,
// 2KB) staged in LDS by waves 0-3 / 8-11, raw s_barrier + lgkmcnt-only drain
// (one barrier per TWO ksteps; in-flight global loads cross barriers freely).
__global__ __launch_bounds__(1024) void poly_main_kernel(const float* __restrict__ X,
                                                         const unsigned short* __restrict__ W,
                                                         const float* __restrict__ C,
                                                         const float* __restrict__ beta,
                                                         const float* __restrict__ Csin,
                                                         float* __restrict__ out) {
    __shared__ __align__(16) char pool[POOL_BYTES];
    // abuf[j] = pool + j*2048, j=0..3 (A slabs, frag-packed bf16)
    // Dmat (float[32][DSTRIDE]) aliases pool after the loop; sinpart at SIN_OFF.

    const int t    = threadIdx.x;
    const int lane = t & 63;
    const int wv   = t >> 6;          // 0..15
    const int kg   = wv >> 3;         // K parity group
    const int cg   = wv & 7;          // col group
    const int ct0  = cg * 3;
    const int row0 = blockIdx.x * BM;

    // A staging: waves 0-3 (p=0, even slabs) and 8-11 (p=1, odd slabs)
    const bool isStage = ((t >> 8) & 1) == 0;
    const int p    = t >> 9;
    const int srow = (t >> 3) & 31;
    const int k4   = (t & 7) << 2;
    const float* xp = X + (size_t)(row0 + srow) * D_DIM + k4;
    const int awfrag = (srow >> 4) * 1024
                     + (((((k4 >> 3) & 3) << 4) | (srow & 15)) * 16) + ((k4 & 7) << 1);

    const s16x8* __restrict__ Wf = (const s16x8*)W;

    f32x4 acc00{}, acc01{}, acc02{}, acc10{}, acc11{}, acc12{};
    float sinacc = 0.f;
    f32x4 xcur{};

    // ---- prologue: stage slabs 0 (p0) / 1 (p1); prefetch X slab 2+p; B slab kg ----
    if (isStage) {
        f32x4 x0 = *(const f32x4*)(xp + (size_t)p * 32);
        sinacc += __sinf(x0.x) + __sinf(x0.y) + __sinf(x0.z) + __sinf(x0.w);
        short4 h;
        h.x = (short)f2bf(x0.x); h.y = (short)f2bf(x0.y);
        h.z = (short)f2bf(x0.z); h.w = (short)f2bf(x0.w);
        *(short4*)(pool + p * 2048 + awfrag) = h;
        xcur = *(const f32x4*)(xp + (size_t)(2 + p) * 32);
    }
    s16x8 bA0 = Wf[((size_t)kg * NT + ct0 + 0) * 64 + lane];
    s16x8 bA1 = Wf[((size_t)kg * NT + ct0 + 1) * 64 + lane];
    s16x8 bA2 = Wf[((size_t)kg * NT + ct0 + 2) * 64 + lane];
    s16x8 bB0{}, bB1{}, bB2{};
    asm volatile("s_waitcnt lgkmcnt(0)" ::: "memory");
    __builtin_amdgcn_s_barrier();
    __builtin_amdgcn_sched_barrier(0);

#define STAGE(d_)                                                               \
    if (isStage) {                                                              \
        const int sw_ = 2 * (d_) + 2 + p;                                       \
        if (sw_ < NSLAB) {                                                      \
            sinacc += __sinf(xcur.x) + __sinf(xcur.y)                           \
                    + __sinf(xcur.z) + __sinf(xcur.w);                          \
            short4 h_;                                                          \
            h_.x = (short)f2bf(xcur.x); h_.y = (short)f2bf(xcur.y);             \
            h_.z = (short)f2bf(xcur.z); h_.w = (short)f2bf(xcur.w);             \
            *(short4*)(pool + (sw_ & 3) * 2048 + awfrag) = h_;                  \
        }                                                                       \
        int sl_ = 2 * (d_) + 4 + p; if (sl_ > NSLAB - 1) sl_ = NSLAB - 1;       \
        xcur = *(const f32x4*)(xp + (size_t)sl_ * 32);                          \
    }

#define BODY(d_, U0, U1, U2, P0, P1, P2)                                        \
    {                                                                           \
        STAGE(d_);                                                              \
        const int ab_ = ((2 * (d_) + kg) & 3) * 2048;                           \
        s16x8 af0_ = *(const s16x8*)(pool + ab_ + lane * 16);                   \
        s16x8 af1_ = *(const s16x8*)(pool + ab_ + 1024 + lane * 16);            \
        acc00 = __builtin_amdgcn_mfma_f32_16x16x32_bf16(af0_, U0, acc00, 0, 0, 0); \
        acc01 = __builtin_amdgcn_mfma_f32_16x16x32_bf16(af0_, U1, acc01, 0, 0, 0); \
        acc02 = __builtin_amdgcn_mfma_f32_16x16x32_bf16(af0_, U2, acc02, 0, 0, 0); \
        acc10 = __builtin_amdgcn_mfma_f32_16x16x32_bf16(af1_, U0, acc10, 0, 0, 0); \
        acc11 = __builtin_amdgcn_mfma_f32_16x16x32_bf16(af1_, U1, acc11, 0, 0, 0); \
        acc12 = __builtin_amdgcn_mfma_f32_16x16x32_bf16(af1_, U2, acc12, 0, 0, 0); \
        int sp_ = 2 * (d_) + 2 + kg; if (sp_ > NSLAB - 1) sp_ = NSLAB - 1;      \
        P0 = Wf[((size_t)sp_ * NT + ct0 + 0) * 64 + lane];                      \
        P1 = Wf[((size_t)sp_ * NT + ct0 + 1) * 64 + lane];                      \
        P2 = Wf[((size_t)sp_ * NT + ct0 + 2) * 64 + lane];                      \
        asm volatile("s_waitcnt lgkmcnt(0)" ::: "memory");                      \
        __builtin_amdgcn_s_barrier();                                           \
        __builtin_amdgcn_sched_barrier(0);                                      \
    }

    for (int e = 0; e < 32; ++e) {
        BODY(2 * e,     bA0, bA1, bA2, bB0, bB1, bB2);
        BODY(2 * e + 1, bB0, bB1, bB2, bA0, bA1, bA2);
    }
#undef BODY
#undef STAGE

    // ---- epilogue ----
    float* Dm = (float*)pool;
    float* sinpart = (float*)(pool + SIN_OFF);
    const f32x4 accA[2][3] = {{acc00, acc01, acc02}, {acc10, acc11, acc12}};
    const int lr4 = (lane >> 4) << 2;
    const int lc  = lane & 15;

    if (kg == 0) {
#pragma unroll
        for (int f = 0; f < 2; ++f)
#pragma unroll
            for (int c = 0; c < 3; ++c) {
                const int col = (ct0 + c) * 16 + lc;
#pragma unroll
                for (int i = 0; i < 4; ++i)
                    Dm[(f * 16 + lr4 + i) * DSTRIDE + col] = accA[f][c][i];
            }
    }
    if (isStage) {
        sinacc += __shfl_xor(sinacc, 1);
        sinacc += __shfl_xor(sinacc, 2);
        sinacc += __shfl_xor(sinacc, 4);
        if ((t & 7) == 0) sinpart[p * 32 + srow] = sinacc;
    }
    __syncthreads();
    if (kg == 1) {
#pragma unroll
        for (int f = 0; f < 2; ++f)
#pragma unroll
            for (int c = 0; c < 3; ++c) {
                const int col = (ct0 + c) * 16 + lc;
#pragma unroll
                for (int i = 0; i < 4; ++i)
                    Dm[(f * 16 + lr4 + i) * DSTRIDE + col] += accA[f][c][i];
            }
    }
    __syncthreads();

    if (t < 512) {
        const int crow = t >> 4;   // 0..31
        const int cc   = t & 15;
        float t1 = 0.f, t2 = 0.f, t3 = 0.f;
#pragma unroll
        for (int rr = 0; rr < 64; rr += 16) {
            const int r = rr + cc;
            t1 += Dm[crow * DSTRIDE + r];
            t2 += Dm[crow * DSTRIDE + 64 + r]  * Dm[crow * DSTRIDE + 128 + r];
            t3 += Dm[crow * DSTRIDE + 192 + r] * Dm[crow * DSTRIDE + 256 + r]
                                               * Dm[crow * DSTRIDE + 320 + r];
        }
#pragma unroll
        for (int off = 1; off < 16; off <<= 1) {
            t1 += __shfl_xor(t1, off, 16);
            t2 += __shfl_xor(t2, off, 16);
            t3 += __shfl_xor(t3, off, 16);
        }
        if (cc == 0)
            out[row0 + crow] = beta[0] + C[0] * t1 + C[1] * t2 + C[2] * t3
                             + Csin[0] * (sinpart[crow] + sinpart[32 + crow]);
    }
}

extern "C" void kernel_launch(void* const* d_in, const int* in_sizes, int n_in,
                              void* d_out, int out_size, void* d_ws, size_t ws_size,
                              hipStream_t stream) {
    const float* X   = (const float*)d_in[0];
    const float* U1  = (const float*)d_in[1];
    const float* U2  = (const float*)d_in[2];
    const float* U3  = (const float*)d_in[3];
    const float* Cc  = (const float*)d_in[4];
    const float* bet = (const float*)d_in[5];
    const float* Cs  = (const float*)d_in[6];
    float* out = (float*)d_out;
    unsigned short* W = (unsigned short*)d_ws;   // 3 MiB bf16, frag-packed

    reg_init_kernel<<<1, 64, 0, stream>>>(Cc, Cs, out + 8192);
    build_w_kernel<<<128 * NT, 64, 0, stream>>>(U1, U2, U3, W, out + 8192);
    poly_main_kernel<<<256, 1024, 0, stream>>>(X, W, Cc, bet, Cs, out);
}

// Round 6
// 93.433 us; speedup vs baseline: 1.6368x; 1.0129x over previous
//
#include <hip/hip_runtime.h>
#include <hip/hip_bf16.h>

typedef float f32x4 __attribute__((ext_vector_type(4)));
typedef short s16x8 __attribute__((ext_vector_type(8)));

#define D_DIM 4096
#define NT 24            // 16-wide col tiles
#define NSLAB 128        // K slabs of 32
#define BM 32
#define DSTRIDE 388      // Dmat row stride (floats)
#define SIN_OFF 49664    // sinpart[2][32] after Dmat 32*388*4
#define POOL_BYTES 49920

__device__ __forceinline__ unsigned short f2bf(float f) {
    unsigned u = __float_as_uint(f);
    u += 0x7fffu + ((u >> 16) & 1u);   // RNE
    return (unsigned short)(u >> 16);
}

__global__ __launch_bounds__(64) void reg_init_kernel(const float* __restrict__ C,
                                                      const float* __restrict__ Csin,
                                                      float* __restrict__ reg_out) {
    if (threadIdx.x == 0)
        reg_out[0] = 0.05f * (fabsf(C[0]) + fabsf(C[1]) + fabsf(C[2]) + fabsf(Csin[0]));
}

// Build W [4096 x 384] bf16, MFMA B-fragment-packed, slab-contiguous:
// chunk = (k>>5)*NT + (n>>4); lane = ((k&31)>>3)*16 | (n&15); j = k&7.
__global__ __launch_bounds__(64) void build_w_kernel(const float* __restrict__ U1,
                                                     const float* __restrict__ U2,
                                                     const float* __restrict__ U3,
                                                     unsigned short* __restrict__ W,
                                                     float* __restrict__ reg_out) {
    const int ks = blockIdx.x / NT;
    const int ct = blockIdx.x % NT;
    const int l  = threadIdx.x;
    const int n  = ct * 16 + (l & 15);
    const int kb = ks * 32 + ((l >> 4) << 3);

    const float* src;
    float scale;
    if (n < 64)       { src = U1 + n;                  scale = 0.01f / 262144.f; }
    else if (n < 128) { src = U2 + (n - 64);           scale = 0.01f / 524288.f; }
    else if (n < 192) { src = U2 + 262144 + (n - 128); scale = 0.01f / 524288.f; }
    else if (n < 256) { src = U3 + (n - 192);          scale = 0.01f / 786432.f; }
    else if (n < 320) { src = U3 + 262144 + (n - 256); scale = 0.01f / 786432.f; }
    else              { src = U3 + 524288 + (n - 320); scale = 0.01f / 786432.f; }

    unsigned short h[8];
    float sabs = 0.f;
#pragma unroll
    for (int j = 0; j < 8; ++j) {
        float u = src[(size_t)(kb + j) * 64];
        sabs += fabsf(u);
        h[j] = f2bf(u);
    }
    uint4 pk;
    pk.x = (unsigned)h[0] | ((unsigned)h[1] << 16);
    pk.y = (unsigned)h[2] | ((unsigned)h[3] << 16);
    pk.z = (unsigned)h[4] | ((unsigned)h[5] << 16);
    pk.w = (unsigned)h[6] | ((unsigned)h[7] << 16);
    *(uint4*)(W + ((size_t)blockIdx.x * 64 + l) * 8) = pk;

    sabs *= scale;
#pragma unroll
    for (int off = 32; off >= 1; off >>= 1)
        sabs += __shfl_xor(sabs, off, 64);
    if (l == 0) atomicAdd(reg_out, sabs);
}

// 1024 thr = 16 waves = 2 K-parity groups (kg) x 8 col-groups (cg, 3 tiles each).
// Deep pipeline: B frags from L2-resident frag-packed W, 3-deep register
// rotation (consumed 2 barrier-intervals after issue); X 3-deep (consumed 3
// intervals after issue, > HBM latency). A slab (32x32 bf16, 2KB) LDS-staged
// 1 interval ahead, 4 buffers. One raw s_barrier + lgkmcnt-only drain per
// interval; in-flight global loads cross barriers freely (no vmcnt drain).
__global__ __launch_bounds__(1024) void poly_main_kernel(const float* __restrict__ X,
                                                         const unsigned short* __restrict__ W,
                                                         const float* __restrict__ C,
                                                         const float* __restrict__ beta,
                                                         const float* __restrict__ Csin,
                                                         float* __restrict__ out) {
    __shared__ __align__(16) char pool[POOL_BYTES];
    // abuf[j] = pool + j*2048, j=0..3 (A slabs, frag-packed bf16)
    // Dmat (float[32][DSTRIDE]) aliases pool after the loop; sinpart at SIN_OFF.

    const int t    = threadIdx.x;
    const int lane = t & 63;
    const int wv   = t >> 6;          // 0..15
    const int kg   = wv >> 3;         // K parity group
    const int cg   = wv & 7;          // col group
    const int ct0  = cg * 3;
    const int row0 = blockIdx.x * BM;

    // A staging: waves 0-3 (p=0, even slabs) and 8-11 (p=1, odd slabs)
    const bool isStage = ((t >> 8) & 1) == 0;
    const int p    = t >> 9;
    const int srow = (t >> 3) & 31;
    const int k4   = (t & 7) << 2;
    const float* xp = X + (size_t)(row0 + srow) * D_DIM + k4;
    const int awfrag = (srow >> 4) * 1024
                     + (((((k4 >> 3) & 3) << 4) | (srow & 15)) * 16) + ((k4 & 7) << 1);

    const s16x8* __restrict__ Wf = (const s16x8*)W;

    f32x4 acc00{}, acc01{}, acc02{}, acc10{}, acc11{}, acc12{};
    float sinacc = 0.f;
    f32x4 xw{}, xa{}, xb{};

    // ---- prologue ----
    if (isStage) {
        f32x4 x0 = *(const f32x4*)(xp + (size_t)p * 32);           // slab p
        sinacc += __sinf(x0.x) + __sinf(x0.y) + __sinf(x0.z) + __sinf(x0.w);
        short4 h;
        h.x = (short)f2bf(x0.x); h.y = (short)f2bf(x0.y);
        h.z = (short)f2bf(x0.z); h.w = (short)f2bf(x0.w);
        *(short4*)(pool + p * 2048 + awfrag) = h;
        xw = *(const f32x4*)(xp + (size_t)(2 + p) * 32);           // write @ d=0
        xa = *(const f32x4*)(xp + (size_t)(4 + p) * 32);           // write @ d=1
        xb = *(const f32x4*)(xp + (size_t)(6 + p) * 32);           // write @ d=2
    }
    s16x8 bA0 = Wf[((size_t)kg * NT + ct0 + 0) * 64 + lane];       // slab kg   (d=0)
    s16x8 bA1 = Wf[((size_t)kg * NT + ct0 + 1) * 64 + lane];
    s16x8 bA2 = Wf[((size_t)kg * NT + ct0 + 2) * 64 + lane];
    s16x8 bB0 = Wf[((size_t)(2 + kg) * NT + ct0 + 0) * 64 + lane]; // slab 2+kg (d=1)
    s16x8 bB1 = Wf[((size_t)(2 + kg) * NT + ct0 + 1) * 64 + lane];
    s16x8 bB2 = Wf[((size_t)(2 + kg) * NT + ct0 + 2) * 64 + lane];
    s16x8 bC0{}, bC1{}, bC2{};
    asm volatile("s_waitcnt lgkmcnt(0)" ::: "memory");
    __builtin_amdgcn_s_barrier();
    __builtin_amdgcn_sched_barrier(0);

// BODY d: stage-write slab 2d+2+p (from XW), reload XW <- slab 2d+8+p (used d+3);
// prefetch B set P <- slab 2d+4+kg (used d+2); compute slab 2d+kg with set U.
#define BODY(d_, U0, U1, U2, P0, P1, P2, XW)                                    \
    {                                                                           \
        const int d__ = (d_);                                                   \
        if (isStage) {                                                          \
            const int sw_ = 2 * d__ + 2 + p;                                    \
            if (sw_ < NSLAB) {                                                  \
                sinacc += __sinf(XW.x) + __sinf(XW.y)                           \
                        + __sinf(XW.z) + __sinf(XW.w);                          \
                short4 h_;                                                      \
                h_.x = (short)f2bf(XW.x); h_.y = (short)f2bf(XW.y);             \
                h_.z = (short)f2bf(XW.z); h_.w = (short)f2bf(XW.w);             \
                *(short4*)(pool + (sw_ & 3) * 2048 + awfrag) = h_;              \
            }                                                                   \
            int sl_ = 2 * d__ + 8 + p; if (sl_ > NSLAB - 1) sl_ = NSLAB - 1;    \
            XW = *(const f32x4*)(xp + (size_t)sl_ * 32);                        \
        }                                                                       \
        int sp_ = 2 * d__ + 4 + kg; if (sp_ > NSLAB - 1) sp_ = NSLAB - 1;       \
        P0 = Wf[((size_t)sp_ * NT + ct0 + 0) * 64 + lane];                      \
        P1 = Wf[((size_t)sp_ * NT + ct0 + 1) * 64 + lane];                      \
        P2 = Wf[((size_t)sp_ * NT + ct0 + 2) * 64 + lane];                      \
        const int ab_ = ((2 * d__ + kg) & 3) * 2048;                            \
        s16x8 af0_ = *(const s16x8*)(pool + ab_ + lane * 16);                   \
        s16x8 af1_ = *(const s16x8*)(pool + ab_ + 1024 + lane * 16);            \
        asm volatile("s_waitcnt lgkmcnt(0)" ::: "memory");                      \
        __builtin_amdgcn_sched_barrier(0);                                      \
        __builtin_amdgcn_s_setprio(1);                                          \
        acc00 = __builtin_amdgcn_mfma_f32_16x16x32_bf16(af0_, U0, acc00, 0, 0, 0); \
        acc01 = __builtin_amdgcn_mfma_f32_16x16x32_bf16(af0_, U1, acc01, 0, 0, 0); \
        acc02 = __builtin_amdgcn_mfma_f32_16x16x32_bf16(af0_, U2, acc02, 0, 0, 0); \
        acc10 = __builtin_amdgcn_mfma_f32_16x16x32_bf16(af1_, U0, acc10, 0, 0, 0); \
        acc11 = __builtin_amdgcn_mfma_f32_16x16x32_bf16(af1_, U1, acc11, 0, 0, 0); \
        acc12 = __builtin_amdgcn_mfma_f32_16x16x32_bf16(af1_, U2, acc12, 0, 0, 0); \
        __builtin_amdgcn_s_setprio(0);                                          \
        __builtin_amdgcn_s_barrier();                                           \
        __builtin_amdgcn_sched_barrier(0);                                      \
    }

    for (int e = 0; e < 21; ++e) {
        BODY(3 * e,     bA0, bA1, bA2, bC0, bC1, bC2, xw);
        BODY(3 * e + 1, bB0, bB1, bB2, bA0, bA1, bA2, xa);
        BODY(3 * e + 2, bC0, bC1, bC2, bB0, bB1, bB2, xb);
    }
    BODY(63, bA0, bA1, bA2, bC0, bC1, bC2, xw);
#undef BODY

    // ---- epilogue ----
    float* Dm = (float*)pool;
    float* sinpart = (float*)(pool + SIN_OFF);
    const f32x4 accA[2][3] = {{acc00, acc01, acc02}, {acc10, acc11, acc12}};
    const int lr4 = (lane >> 4) << 2;
    const int lc  = lane & 15;

    if (kg == 0) {
#pragma unroll
        for (int f = 0; f < 2; ++f)
#pragma unroll
            for (int c = 0; c < 3; ++c) {
                const int col = (ct0 + c) * 16 + lc;
#pragma unroll
                for (int i = 0; i < 4; ++i)
                    Dm[(f * 16 + lr4 + i) * DSTRIDE + col] = accA[f][c][i];
            }
    }
    if (isStage) {
        sinacc += __shfl_xor(sinacc, 1);
        sinacc += __shfl_xor(sinacc, 2);
        sinacc += __shfl_xor(sinacc, 4);
        if ((t & 7) == 0) sinpart[p * 32 + srow] = sinacc;
    }
    __syncthreads();
    if (kg == 1) {
#pragma unroll
        for (int f = 0; f < 2; ++f)
#pragma unroll
            for (int c = 0; c < 3; ++c) {
                const int col = (ct0 + c) * 16 + lc;
#pragma unroll
                for (int i = 0; i < 4; ++i)
                    Dm[(f * 16 + lr4 + i) * DSTRIDE + col] += accA[f][c][i];
            }
    }
    __syncthreads();

    if (t < 512) {
        const int crow = t >> 4;   // 0..31
        const int cc   = t & 15;
        float t1 = 0.f, t2 = 0.f, t3 = 0.f;
#pragma unroll
        for (int rr = 0; rr < 64; rr += 16) {
            const int r = rr + cc;
            t1 += Dm[crow * DSTRIDE + r];
            t2 += Dm[crow * DSTRIDE + 64 + r]  * Dm[crow * DSTRIDE + 128 + r];
            t3 += Dm[crow * DSTRIDE + 192 + r] * Dm[crow * DSTRIDE + 256 + r]
                                               * Dm[crow * DSTRIDE + 320 + r];
        }
#pragma unroll
        for (int off = 1; off < 16; off <<= 1) {
            t1 += __shfl_xor(t1, off, 16);
            t2 += __shfl_xor(t2, off, 16);
            t3 += __shfl_xor(t3, off, 16);
        }
        if (cc == 0)
            out[row0 + crow] = beta[0] + C[0] * t1 + C[1] * t2 + C[2] * t3
                             + Csin[0] * (sinpart[crow] + sinpart[32 + crow]);
    }
}

extern "C" void kernel_launch(void* const* d_in, const int* in_sizes, int n_in,
                              void* d_out, int out_size, void* d_ws, size_t ws_size,
                              hipStream_t stream) {
    const float* X   = (const float*)d_in[0];
    const float* U1  = (const float*)d_in[1];
    const float* U2  = (const float*)d_in[2];
    const float* U3  = (const float*)d_in[3];
    const float* Cc  = (const float*)d_in[4];
    const float* bet = (const float*)d_in[5];
    const float* Cs  = (const float*)d_in[6];
    float* out = (float*)d_out;
    unsigned short* W = (unsigned short*)d_ws;   // 3 MiB bf16, frag-packed

    reg_init_kernel<<<1, 64, 0, stream>>>(Cc, Cs, out + 8192);
    build_w_kernel<<<128 * NT, 64, 0, stream>>>(U1, U2, U3, W, out + 8192);
    poly_main_kernel<<<256, 1024, 0, stream>>>(X, W, Cc, bet, Cs, out);
}